// Round 3
// baseline (1111.767 us; speedup 1.0000x reference)
//
#include <hip/hip_runtime.h>
#include <hip/hip_bf16.h>

typedef __hip_bfloat16 bf16;
typedef __attribute__((ext_vector_type(8))) short bfrag;   // 8 bf16 = 4 VGPRs
typedef __attribute__((ext_vector_type(4))) float ffrag;   // 4 fp32 acc

#define CDIM 128
#define TDIMC 64
#define MSGD 64

__device__ __forceinline__ unsigned short f2bf(float f) {
    union { __hip_bfloat16 h; unsigned short u; } cv;
    cv.h = __float2bfloat16(f);
    return cv.u;
}

// ---------------- edge_index dtype detection + conversion ----------------
__global__ void detect_kernel(const int* __restrict__ ei, int samp, int* __restrict__ flag) {
    int i = blockIdx.x * blockDim.x + threadIdx.x;
    if (i < samp) {
        if (ei[2 * i + 1] != 0) atomicOr(flag, 1);
    }
}

__global__ void convert_kernel(const int* __restrict__ ei, int E, const int* __restrict__ flag,
                               int* __restrict__ src32, int* __restrict__ dst32) {
    int i = blockIdx.x * blockDim.x + threadIdx.x;
    if (i >= 2 * E) return;
    int is32 = *flag;
    int val = is32 ? ei[i] : ei[2 * i];
    if (i < E) src32[i] = val;
    else       dst32[i - E] = val;
}

// ---------------- weight pre-transpose + bf16 convert ----------------
// Wt[mat][n][k] = W_mat[k][n] as bf16 (mat 0..3 = q,k,v,skip), Wet[n][k] = We[k][n]
__global__ void wconv_kernel(const float* __restrict__ Wq, const float* __restrict__ Wk,
                             const float* __restrict__ Wv, const float* __restrict__ Ws,
                             const float* __restrict__ We,
                             short* __restrict__ Wt, short* __restrict__ Wet) {
    int idx = blockIdx.x * 256 + threadIdx.x;
    if (idx >= 5 * 16384) return;
    int mat = idx >> 14;
    int r = idx & 16383;
    int n = r >> 7, kk = r & 127;
    const float* W = (mat == 0) ? Wq : (mat == 1) ? Wk : (mat == 2) ? Wv : (mat == 3) ? Ws : We;
    short bv = (short)f2bf(W[kk * 128 + n]);
    if (mat < 4) Wt[(size_t)mat * 16384 + n * 128 + kk] = bv;
    else         Wet[n * 128 + kk] = bv;
}

// ---------------- MFMA node projections: wave w -> {q,k,v,skip->out} ----------------
// Block 256 = 4 waves, 64 nodes. Each wave: sx[64x128] @ Wt_w -> 64x128.
__global__ __launch_bounds__(256)
void proj_kernel(const float* __restrict__ x, const short* __restrict__ Wt,
                 const float* __restrict__ bq, const float* __restrict__ bk,
                 const float* __restrict__ bv, const float* __restrict__ bs,
                 float* __restrict__ q, float* __restrict__ k, float* __restrict__ v,
                 float* __restrict__ out, int N) {
    __shared__ __attribute__((aligned(16))) short sx[64][136];  // +8 pad: 2-way LDS (free)
    int tid = threadIdx.x;
    int n0 = blockIdx.x * 64;
    const float4* x4 = (const float4*)x;
    for (int i = tid; i < 64 * 32; i += 256) {
        int nl = i >> 5, c4 = i & 31;
        int n = n0 + nl;
        float4 f = (n < N) ? x4[(size_t)n * 32 + c4] : make_float4(0.f, 0.f, 0.f, 0.f);
        unsigned int lo = ((unsigned int)f2bf(f.y) << 16) | f2bf(f.x);
        unsigned int hi = ((unsigned int)f2bf(f.w) << 16) | f2bf(f.z);
        *(uint2*)&sx[nl][c4 * 4] = make_uint2(lo, hi);
    }
    __syncthreads();

    int lane = tid & 63, wv = tid >> 6;
    int n15 = lane & 15, quad = lane >> 4;
    const short* W = Wt + (size_t)wv * 16384;
    const float* bias = (wv == 0) ? bq : (wv == 1) ? bk : (wv == 2) ? bv : bs;
    float* dstp = (wv == 0) ? q : (wv == 1) ? k : (wv == 2) ? v : out;

    ffrag acc[4][8];
#pragma unroll
    for (int r = 0; r < 4; ++r)
#pragma unroll
        for (int c = 0; c < 8; ++c)
            acc[r][c] = (ffrag){0.f, 0.f, 0.f, 0.f};

#pragma unroll
    for (int kc = 0; kc < 4; ++kc) {
        int kk = kc * 32 + quad * 8;
        bfrag a[4];
#pragma unroll
        for (int r = 0; r < 4; ++r)
            a[r] = *(const bfrag*)&sx[r * 16 + n15][kk];
#pragma unroll
        for (int c = 0; c < 8; ++c) {
            bfrag b = *(const bfrag*)&W[(c * 16 + n15) * 128 + kk];
#pragma unroll
            for (int r = 0; r < 4; ++r)
                acc[r][c] = __builtin_amdgcn_mfma_f32_16x16x32_bf16(a[r], b, acc[r][c], 0, 0, 0);
        }
    }

#pragma unroll
    for (int c = 0; c < 8; ++c) {
        int col = c * 16 + n15;
        float bval = bias[col];
#pragma unroll
        for (int r = 0; r < 4; ++r) {
#pragma unroll
            for (int g = 0; g < 4; ++g) {
                int n = n0 + r * 16 + quad * 4 + g;
                if (n < N) dstp[(size_t)n * CDIM + col] = acc[r][c][g] + bval;
            }
        }
    }
}

// ---------------- MFMA edge kernel ----------------
// Block 256 = 4 waves, 64 edges (E = 9375*64 exactly for this problem, guards kept).
// Phase 1: edge_attr = [cos(relt*w+b), msg[e]] -> bf16 LDS
// Phase 2: wave wv computes e = sattr[16 rows] @ Wet -> LDS (its own rows only)
// Phase 3 (same wave, no barrier): gather k/q/v, kv=k+e, p=q*kv, shfl-reduce per head,
//          exp -> ex + denom atomic; ve = bf16(v+e) -> global
__global__ __launch_bounds__(256)
void edge_kernel(const int* __restrict__ src, const int* __restrict__ dst,
                 const int* __restrict__ tarr, const int* __restrict__ last_update,
                 const float* __restrict__ msg,
                 const float* __restrict__ time_w, const float* __restrict__ time_b,
                 const short* __restrict__ Wet,
                 const float* __restrict__ q, const float* __restrict__ k, const float* __restrict__ v,
                 bf16* __restrict__ ve, float* __restrict__ ex, float* __restrict__ denom,
                 int E) {
    __shared__ __attribute__((aligned(16))) short sattr[64][136];
    __shared__ __attribute__((aligned(16))) float se[64][130];
    __shared__ int s_src[64], s_dst[64];
    __shared__ float s_relt[64];
    int tid = threadIdx.x;
    int e0 = blockIdx.x * 64;

    if (tid < 64) {
        int e = e0 + tid;
        int s = 0, d = 0;
        float rt = 0.f;
        if (e < E) {
            s = src[e];
            d = dst[e];
            rt = (float)(last_update[s] - tarr[e]);
        }
        s_src[tid] = s; s_dst[tid] = d; s_relt[tid] = rt;
    }
    __syncthreads();

    for (int i = tid; i < 64 * CDIM; i += 256) {
        int el = i >> 7, c = i & 127;
        int e = e0 + el;
        float val;
        if (c < TDIMC) val = cosf(s_relt[el] * time_w[c] + time_b[c]);
        else           val = (e < E) ? msg[(size_t)e * MSGD + (c - TDIMC)] : 0.f;
        sattr[el][c] = (short)f2bf(val);
    }
    __syncthreads();

    int lane = tid & 63;
    int wv = tid >> 6;            // wave id -> edges wv*16 .. wv*16+15
    int n15 = lane & 15, quad = lane >> 4;

    ffrag acc[8];
#pragma unroll
    for (int c = 0; c < 8; ++c) acc[c] = (ffrag){0.f, 0.f, 0.f, 0.f};
#pragma unroll
    for (int kc = 0; kc < 4; ++kc) {
        int kk = kc * 32 + quad * 8;
        bfrag a = *(const bfrag*)&sattr[wv * 16 + n15][kk];
#pragma unroll
        for (int c = 0; c < 8; ++c) {
            bfrag b = *(const bfrag*)&Wet[(c * 16 + n15) * 128 + kk];
            acc[c] = __builtin_amdgcn_mfma_f32_16x16x32_bf16(a, b, acc[c], 0, 0, 0);
        }
    }
    // C layout: col = c*16 + (lane&15), row(tile) = quad*4 + reg  -> wave's own rows
#pragma unroll
    for (int c = 0; c < 8; ++c)
#pragma unroll
        for (int r = 0; r < 4; ++r)
            se[wv * 16 + quad * 4 + r][c * 16 + n15] = acc[c][r];
    // no barrier: this wave reads only rows it wrote (compiler emits lgkmcnt waits)

    int h = lane >> 5;            // head for cols {2*lane, 2*lane+1}
    for (int j = 0; j < 16; ++j) {
        int el = wv * 16 + j;
        int e = e0 + el;
        int s = s_src[el], d = s_dst[el];
        float2 ev = *(const float2*)&se[el][2 * lane];
        float2 kv = *(const float2*)&k[(size_t)s * CDIM + 2 * lane];
        float2 qv = *(const float2*)&q[(size_t)d * CDIM + 2 * lane];
        float2 vv = *(const float2*)&v[(size_t)s * CDIM + 2 * lane];
        kv.x += ev.x; kv.y += ev.y;
        float p = qv.x * kv.x + qv.y * kv.y;
        vv.x += ev.x; vv.y += ev.y;
        if (e < E) {
            unsigned int pk = ((unsigned int)f2bf(vv.y) << 16) | f2bf(vv.x);
            ((unsigned int*)ve)[(size_t)e * 64 + lane] = pk;
        }
#pragma unroll
        for (int off = 1; off < 32; off <<= 1) p += __shfl_xor(p, off, 32);
        float exv = expf(p * 0.125f);   // 1/sqrt(64); no segment-max needed (|alpha| ~< 8)
        if (e < E && (lane == 0 || lane == 32)) {
            ex[e * 2 + h] = exv;
            atomicAdd(&denom[d * 2 + h], exv);
        }
    }
}

// ---------------- aggregation: out[dst] += ve * attn ----------------
__global__ __launch_bounds__(256)
void agg_kernel(const int* __restrict__ dst, const bf16* __restrict__ ve,
                const float* __restrict__ ex, const float* __restrict__ denom,
                float* __restrict__ out, int E) {
    int tid = threadIdx.x;
    int e = blockIdx.x * 2 + (tid >> 7);
    if (e >= E) return;
    int c = tid & 127;
    int d = dst[e];
    int h = c >> 6;
    float exv = ex[e * 2 + h];
    float den = denom[d * 2 + h];
    float attn = exv / (den + 1e-16f);
    float val = __bfloat162float(ve[(size_t)e * CDIM + c]) * attn;
    atomicAdd(&out[(size_t)d * CDIM + c], val);
}

extern "C" void kernel_launch(void* const* d_in, const int* in_sizes, int n_in,
                              void* d_out, int out_size, void* d_ws, size_t ws_size,
                              hipStream_t stream) {
    const float* x       = (const float*)d_in[0];
    const int*   last_up = (const int*)d_in[1];
    const int*   ei      = (const int*)d_in[2];
    const int*   tarr    = (const int*)d_in[3];
    const float* msg     = (const float*)d_in[4];
    const float* time_w  = (const float*)d_in[5];
    const float* time_b  = (const float*)d_in[6];
    const float* Wq = (const float*)d_in[7];  const float* bq = (const float*)d_in[8];
    const float* Wk = (const float*)d_in[9];  const float* bk = (const float*)d_in[10];
    const float* Wv = (const float*)d_in[11]; const float* bv = (const float*)d_in[12];
    const float* We = (const float*)d_in[13];
    const float* Wskip = (const float*)d_in[14]; const float* bskip = (const float*)d_in[15];
    float* out = (float*)d_out;

    int N = in_sizes[0] / CDIM;
    int E = in_sizes[3];

    char* ws = (char*)d_ws;
    size_t off = 0;
    float* q_    = (float*)(ws + off); off += (size_t)N * CDIM * 4;
    float* k_    = (float*)(ws + off); off += (size_t)N * CDIM * 4;
    float* v_    = (float*)(ws + off); off += (size_t)N * CDIM * 4;
    bf16*  ve    = (bf16*)(ws + off);  off += (size_t)E * CDIM * 2;
    float* ex    = (float*)(ws + off); off += (size_t)E * 2 * 4;
    float* denom = (float*)(ws + off); off += (size_t)N * 2 * 4;
    int*   flag  = (int*)(ws + off);   off += 128;
    int*   src32 = (int*)(ws + off);   off += (size_t)E * 4;
    int*   dst32 = (int*)(ws + off);   off += (size_t)E * 4;
    short* Wt    = (short*)(ws + off); off += 4 * 16384 * 2;
    short* Wet   = (short*)(ws + off); off += 16384 * 2;

    // zero denom + flag (contiguous)
    hipMemsetAsync(denom, 0, (size_t)N * 2 * 4 + 128, stream);

    int samp = E < 65536 ? E : 65536;
    detect_kernel<<<(samp + 255) / 256, 256, 0, stream>>>(ei, samp, flag);
    convert_kernel<<<(2 * E + 255) / 256, 256, 0, stream>>>(ei, E, flag, src32, dst32);
    wconv_kernel<<<(5 * 16384 + 255) / 256, 256, 0, stream>>>(Wq, Wk, Wv, Wskip, We, Wt, Wet);
    proj_kernel<<<(N + 63) / 64, 256, 0, stream>>>(x, Wt, bq, bk, bv, bskip,
                                                   q_, k_, v_, out, N);
    edge_kernel<<<(E + 63) / 64, 256, 0, stream>>>(src32, dst32, tarr, last_up, msg,
                                                   time_w, time_b, Wet, q_, k_, v_,
                                                   ve, ex, denom, E);
    agg_kernel<<<(E + 1) / 2, 256, 0, stream>>>(dst32, ve, ex, denom, out, E);
}

// Round 5
// 918.345 us; speedup vs baseline: 1.2106x; 1.2106x over previous
//
#include <hip/hip_runtime.h>
#include <hip/hip_bf16.h>

typedef __hip_bfloat16 bf16;
typedef __attribute__((ext_vector_type(8))) short bfrag;   // 8 bf16 = 4 VGPRs
typedef __attribute__((ext_vector_type(4))) float ffrag;   // 4 fp32 acc

#define CDIM 128
#define TDIMC 64
#define MSGD 64

__device__ __forceinline__ unsigned short f2bf(float f) {
    union { __hip_bfloat16 h; unsigned short u; } cv;
    cv.h = __float2bfloat16(f);
    return cv.u;
}

// ---------------- edge_index dtype detection + conversion + dst histogram ----------------
__global__ void detect_kernel(const int* __restrict__ ei, int samp, int* __restrict__ flag) {
    int i = blockIdx.x * blockDim.x + threadIdx.x;
    if (i < samp) {
        if (ei[2 * i + 1] != 0) atomicOr(flag, 1);
    }
}

__global__ void convert_hist_kernel(const int* __restrict__ ei, int E, const int* __restrict__ flag,
                                    int* __restrict__ src32, int* __restrict__ dst32,
                                    int* __restrict__ count) {
    int i = blockIdx.x * blockDim.x + threadIdx.x;
    if (i >= 2 * E) return;
    int is32 = *flag;
    int val = is32 ? ei[i] : ei[2 * i];
    if (i < E) src32[i] = val;
    else {
        dst32[i - E] = val;
        atomicAdd(&count[val], 1);
    }
}

// ---------------- exclusive scan over count[N] -> rowptr[N+1], cur[N] ----------------
__global__ __launch_bounds__(1024)
void scan_kernel(const int* __restrict__ count, int N, int E,
                 int* __restrict__ rowptr, int* __restrict__ cur) {
    __shared__ int wsum[16];
    __shared__ int woff[16];
    __shared__ int carry;
    int t = threadIdx.x;
    int lane = t & 63, wv = t >> 6;
    if (t == 0) carry = 0;
    __syncthreads();
    for (int base = 0; base < N; base += 1024) {
        int i = base + t;
        int v = (i < N) ? count[i] : 0;
        int incl = v;
#pragma unroll
        for (int off = 1; off < 64; off <<= 1) {
            int n = __shfl_up(incl, off, 64);
            if (lane >= off) incl += n;
        }
        if (lane == 63) wsum[wv] = incl;
        __syncthreads();
        if (wv == 0) {
            int ws = (lane < 16) ? wsum[lane] : 0;
            int wi = ws;
#pragma unroll
            for (int off = 1; off < 16; off <<= 1) {
                int n = __shfl_up(wi, off, 64);
                if (lane >= off) wi += n;
            }
            if (lane < 16) woff[lane] = wi - ws;   // exclusive wave offset
        }
        __syncthreads();
        int excl = carry + woff[wv] + incl - v;
        if (i < N) { rowptr[i] = excl; cur[i] = excl; }
        __syncthreads();
        if (t == 1023) carry = excl + v;
        __syncthreads();
    }
    if (t == 0) rowptr[N] = E;
}

// ---------------- scatter into dst-sorted order ----------------
__global__ void scatter_kernel(const int* __restrict__ src32, const int* __restrict__ dst32,
                               const int* __restrict__ tarr, int* __restrict__ cur,
                               int* __restrict__ perm, int* __restrict__ src_s,
                               int* __restrict__ dst_s, int* __restrict__ t_s, int E) {
    int e = blockIdx.x * 256 + threadIdx.x;
    if (e >= E) return;
    int d = dst32[e];
    int pos = atomicAdd(&cur[d], 1);
    perm[pos] = e;
    src_s[pos] = src32[e];
    dst_s[pos] = d;
    t_s[pos] = tarr[e];
}

// ---------------- weight pre-transpose + bf16 convert ----------------
__global__ void wconv_kernel(const float* __restrict__ Wq, const float* __restrict__ Wk,
                             const float* __restrict__ Wv, const float* __restrict__ Ws,
                             const float* __restrict__ We,
                             short* __restrict__ Wt, short* __restrict__ Wet) {
    int idx = blockIdx.x * 256 + threadIdx.x;
    if (idx >= 5 * 16384) return;
    int mat = idx >> 14;
    int r = idx & 16383;
    int n = r >> 7, kk = r & 127;
    const float* W = (mat == 0) ? Wq : (mat == 1) ? Wk : (mat == 2) ? Wv : (mat == 3) ? Ws : We;
    short bv = (short)f2bf(W[kk * 128 + n]);
    if (mat < 4) Wt[(size_t)mat * 16384 + n * 128 + kk] = bv;
    else         Wet[n * 128 + kk] = bv;
}

// ---------------- MFMA node projections: wave w -> {q,k,v,skip->out} ----------------
__global__ __launch_bounds__(256)
void proj_kernel(const float* __restrict__ x, const short* __restrict__ Wt,
                 const float* __restrict__ bq, const float* __restrict__ bk,
                 const float* __restrict__ bv, const float* __restrict__ bs,
                 float* __restrict__ q, float* __restrict__ k, float* __restrict__ v,
                 float* __restrict__ out, int N) {
    __shared__ __attribute__((aligned(16))) short sx[64][136];
    int tid = threadIdx.x;
    int n0 = blockIdx.x * 64;
    const float4* x4 = (const float4*)x;
    for (int i = tid; i < 64 * 32; i += 256) {
        int nl = i >> 5, c4 = i & 31;
        int n = n0 + nl;
        float4 f = (n < N) ? x4[(size_t)n * 32 + c4] : make_float4(0.f, 0.f, 0.f, 0.f);
        unsigned int lo = ((unsigned int)f2bf(f.y) << 16) | f2bf(f.x);
        unsigned int hi = ((unsigned int)f2bf(f.w) << 16) | f2bf(f.z);
        *(uint2*)&sx[nl][c4 * 4] = make_uint2(lo, hi);
    }
    __syncthreads();

    int lane = tid & 63, wv = tid >> 6;
    int n15 = lane & 15, quad = lane >> 4;
    const short* W = Wt + (size_t)wv * 16384;
    const float* bias = (wv == 0) ? bq : (wv == 1) ? bk : (wv == 2) ? bv : bs;
    float* dstp = (wv == 0) ? q : (wv == 1) ? k : (wv == 2) ? v : out;

    ffrag acc[4][8];
#pragma unroll
    for (int r = 0; r < 4; ++r)
#pragma unroll
        for (int c = 0; c < 8; ++c)
            acc[r][c] = (ffrag){0.f, 0.f, 0.f, 0.f};

#pragma unroll
    for (int kc = 0; kc < 4; ++kc) {
        int kk = kc * 32 + quad * 8;
        bfrag a[4];
#pragma unroll
        for (int r = 0; r < 4; ++r)
            a[r] = *(const bfrag*)&sx[r * 16 + n15][kk];
#pragma unroll
        for (int c = 0; c < 8; ++c) {
            bfrag b = *(const bfrag*)&W[(c * 16 + n15) * 128 + kk];
#pragma unroll
            for (int r = 0; r < 4; ++r)
                acc[r][c] = __builtin_amdgcn_mfma_f32_16x16x32_bf16(a[r], b, acc[r][c], 0, 0, 0);
        }
    }

#pragma unroll
    for (int c = 0; c < 8; ++c) {
        int col = c * 16 + n15;
        float bval = bias[col];
#pragma unroll
        for (int r = 0; r < 4; ++r) {
#pragma unroll
            for (int g = 0; g < 4; ++g) {
                int n = n0 + r * 16 + quad * 4 + g;
                if (n < N) dstp[(size_t)n * CDIM + col] = acc[r][c][g] + bval;
            }
        }
    }
}

// ---------------- MFMA edge kernel (dst-sorted order) ----------------
// Block 256 = 4 waves, 64 sorted edges. Single bf16 LDS buffer: sattr, then e overlaid.
// The overlay WRITE needs no barrier (every write transitively depends on all A-frag
// ds_reads via the MFMA chain). The phase-3 READ of e DOES need a barrier: without it
// the compiler may hoist lane-locally-disjoint ds_reads above other lanes' overlay
// writes (SIMT race — this was Round 4's absmax=3.2 bug).
__global__ __launch_bounds__(256)
void edge_kernel(const int* __restrict__ src_s, const int* __restrict__ dst_s,
                 const int* __restrict__ t_s, const int* __restrict__ perm,
                 const int* __restrict__ last_update,
                 const float* __restrict__ msg,
                 const float* __restrict__ time_w, const float* __restrict__ time_b,
                 const short* __restrict__ Wet,
                 const float* __restrict__ q, const float* __restrict__ k, const float* __restrict__ v,
                 unsigned int* __restrict__ ve2, float* __restrict__ exs,
                 int E) {
    __shared__ __attribute__((aligned(16))) short sbuf[64][136];
    __shared__ int s_src[64], s_dst[64], s_perm[64];
    __shared__ float s_relt[64];
    int tid = threadIdx.x;
    int e0 = blockIdx.x * 64;

    if (tid < 64) {
        int e = e0 + tid;
        int s = 0, d = 0, p = 0;
        float rt = 0.f;
        if (e < E) {
            s = src_s[e];
            d = dst_s[e];
            p = perm[e];
            rt = (float)(last_update[s] - t_s[e]);
        }
        s_src[tid] = s; s_dst[tid] = d; s_perm[tid] = p; s_relt[tid] = rt;
    }
    __syncthreads();

    for (int i = tid; i < 64 * CDIM; i += 256) {
        int el = i >> 7, c = i & 127;
        float val;
        if (c < TDIMC) val = cosf(s_relt[el] * time_w[c] + time_b[c]);
        else           val = msg[(size_t)s_perm[el] * MSGD + (c - TDIMC)];
        sbuf[el][c] = (short)f2bf(val);
    }
    __syncthreads();

    int lane = tid & 63;
    int wv = tid >> 6;            // wave -> edges wv*16 .. wv*16+15
    int n15 = lane & 15, quad = lane >> 4;

    ffrag acc[8];
#pragma unroll
    for (int c = 0; c < 8; ++c) acc[c] = (ffrag){0.f, 0.f, 0.f, 0.f};
#pragma unroll
    for (int kc = 0; kc < 4; ++kc) {
        int kk = kc * 32 + quad * 8;
        bfrag a = *(const bfrag*)&sbuf[wv * 16 + n15][kk];
#pragma unroll
        for (int c = 0; c < 8; ++c) {
            bfrag b = *(const bfrag*)&Wet[(c * 16 + n15) * 128 + kk];
            acc[c] = __builtin_amdgcn_mfma_f32_16x16x32_bf16(a, b, acc[c], 0, 0, 0);
        }
    }
    // Overlay e (bf16) onto this wave's rows. C layout: col=c*16+n15, row=quad*4+r.
#pragma unroll
    for (int c = 0; c < 8; ++c)
#pragma unroll
        for (int r = 0; r < 4; ++r)
            sbuf[wv * 16 + quad * 4 + r][c * 16 + n15] = (short)f2bf(acc[c][r]);

    __syncthreads();   // REQUIRED: orders overlay writes before cross-lane e reads

    int h = lane >> 5;            // head for cols {2*lane, 2*lane+1}
#pragma unroll
    for (int jb = 0; jb < 16; jb += 4) {
        float2 kv[4], qv[4], vv[4];
        unsigned int ep[4];
        int eidx[4];
#pragma unroll
        for (int u = 0; u < 4; ++u) {
            int el = wv * 16 + jb + u;
            eidx[u] = e0 + el;
            int s = s_src[el], d = s_dst[el];
            ep[u] = *(const unsigned int*)&sbuf[el][2 * lane];
            kv[u] = *(const float2*)&k[(size_t)s * CDIM + 2 * lane];
            qv[u] = *(const float2*)&q[(size_t)d * CDIM + 2 * lane];
            vv[u] = *(const float2*)&v[(size_t)s * CDIM + 2 * lane];
        }
#pragma unroll
        for (int u = 0; u < 4; ++u) {
            float ex0 = __uint_as_float(ep[u] << 16);
            float ex1 = __uint_as_float(ep[u] & 0xffff0000u);
            float kx = kv[u].x + ex0, ky = kv[u].y + ex1;
            float p = qv[u].x * kx + qv[u].y * ky;
            float vx = vv[u].x + ex0, vy = vv[u].y + ex1;
            unsigned int pk = ((unsigned int)f2bf(vy) << 16) | f2bf(vx);
            if (eidx[u] < E) ve2[(size_t)eidx[u] * 64 + lane] = pk;
#pragma unroll
            for (int off = 1; off < 32; off <<= 1) p += __shfl_xor(p, off, 32);
            float exv = expf(p * 0.125f);   // 1/sqrt(64); |alpha| bounded ~8, no seg-max
            if (eidx[u] < E && (lane == 0 || lane == 32)) exs[eidx[u] * 2 + h] = exv;
        }
    }
}

// ---------------- CSR aggregation: one wave per node, no atomics ----------------
__global__ __launch_bounds__(256)
void agg_kernel(const int* __restrict__ rowptr, const unsigned int* __restrict__ ve2,
                const float* __restrict__ exs, float* __restrict__ out, int N) {
    int wv = threadIdx.x >> 6, lane = threadIdx.x & 63;
    int d = blockIdx.x * 4 + wv;
    if (d >= N) return;
    int beg = rowptr[d], end = rowptr[d + 1];
    int h = lane >> 5;
    float accx = 0.f, accy = 0.f, den = 0.f;
    for (int i = beg; i < end; ++i) {
        float ev = exs[i * 2 + h];
        unsigned int pk = ve2[(size_t)i * 64 + lane];
        float vx = __uint_as_float(pk << 16);
        float vy = __uint_as_float(pk & 0xffff0000u);
        accx = fmaf(vx, ev, accx);
        accy = fmaf(vy, ev, accy);
        den += ev;
    }
    float inv = 1.f / (den + 1e-16f);
    float2* op = (float2*)&out[(size_t)d * CDIM + 2 * lane];
    float2 o = *op;
    o.x += accx * inv;
    o.y += accy * inv;
    *op = o;
}

extern "C" void kernel_launch(void* const* d_in, const int* in_sizes, int n_in,
                              void* d_out, int out_size, void* d_ws, size_t ws_size,
                              hipStream_t stream) {
    const float* x       = (const float*)d_in[0];
    const int*   last_up = (const int*)d_in[1];
    const int*   ei      = (const int*)d_in[2];
    const int*   tarr    = (const int*)d_in[3];
    const float* msg     = (const float*)d_in[4];
    const float* time_w  = (const float*)d_in[5];
    const float* time_b  = (const float*)d_in[6];
    const float* Wq = (const float*)d_in[7];  const float* bq = (const float*)d_in[8];
    const float* Wk = (const float*)d_in[9];  const float* bk = (const float*)d_in[10];
    const float* Wv = (const float*)d_in[11]; const float* bv = (const float*)d_in[12];
    const float* We = (const float*)d_in[13];
    const float* Wskip = (const float*)d_in[14]; const float* bskip = (const float*)d_in[15];
    float* out = (float*)d_out;

    int N = in_sizes[0] / CDIM;
    int E = in_sizes[3];

    char* ws = (char*)d_ws;
    size_t off = 0;
#define ALLOC(ptr, type, nelem) type* ptr = (type*)(ws + off); off = (off + (size_t)(nelem) * sizeof(type) + 255) & ~(size_t)255
    ALLOC(q_,    float, (size_t)N * CDIM);
    ALLOC(k_,    float, (size_t)N * CDIM);
    ALLOC(v_,    float, (size_t)N * CDIM);
    ALLOC(ve2,   unsigned int, (size_t)E * 64);
    ALLOC(exs,   float, (size_t)E * 2);
    ALLOC(count, int,   N + 64);          // flag lives right after count (one memset)
    int* flag = count + N;
    ALLOC(rowptr, int,  N + 1);
    ALLOC(cur,    int,  N);
    ALLOC(src32,  int,  E);
    ALLOC(dst32,  int,  E);
    ALLOC(perm,   int,  E);
    ALLOC(src_s,  int,  E);
    ALLOC(dst_s,  int,  E);
    ALLOC(t_s,    int,  E);
    ALLOC(Wt,     short, 4 * 16384);
    ALLOC(Wet,    short, 16384);
#undef ALLOC

    // zero count + flag (ws is poisoned 0xAA before each timed call)
    hipMemsetAsync(count, 0, (size_t)(N + 64) * 4, stream);

    int samp = E < 65536 ? E : 65536;
    detect_kernel<<<(samp + 255) / 256, 256, 0, stream>>>(ei, samp, flag);
    convert_hist_kernel<<<(2 * E + 255) / 256, 256, 0, stream>>>(ei, E, flag, src32, dst32, count);
    scan_kernel<<<1, 1024, 0, stream>>>(count, N, E, rowptr, cur);
    scatter_kernel<<<(E + 255) / 256, 256, 0, stream>>>(src32, dst32, tarr, cur,
                                                        perm, src_s, dst_s, t_s, E);
    wconv_kernel<<<(5 * 16384 + 255) / 256, 256, 0, stream>>>(Wq, Wk, Wv, Wskip, We, Wt, Wet);
    proj_kernel<<<(N + 63) / 64, 256, 0, stream>>>(x, Wt, bq, bk, bv, bskip,
                                                   q_, k_, v_, out, N);
    edge_kernel<<<(E + 63) / 64, 256, 0, stream>>>(src_s, dst_s, t_s, perm, last_up, msg,
                                                   time_w, time_b, Wet, q_, k_, v_,
                                                   ve2, exs, E);
    agg_kernel<<<(N + 3) / 4, 256, 0, stream>>>(rowptr, ve2, exs, out, N);
}